// Round 12
// baseline (78.496 us; speedup 1.0000x reference)
//
#include <hip/hip_runtime.h>
#include <hip/hip_bf16.h>

// RetinaNet focal classification loss, MI355X. Output: scalar f32.
//
// Round-12: grid shaped to the residency quantum. At VGPR>=64 the CU holds
// 4 waves/SIMD -> 1024 blocks resident per round; r7's 1568-block grid ran
// 1 full + 1 partial round (both r3 and r7 landed at ~42% of their issue
// floors). Here: 64x16 = 1024 blocks = exactly 4 blocks/CU, one round, no
// tail. APT=13 (block covers 3328 anchors; blocks past A_N do masked dead
// work, preserving perfect balance). __launch_bounds__(256,4) pins the
// allocator at <=128 VGPR (guards against r11's 240-VGPR hoist; live-set
// ~95-115, no outer-loop LICM so no r5-style spill). #pragma unroll 8 keeps
// the j-body ~11KB (I$-resident) and bounds LDS-value hoisting. probs loads
// in the epilogue (frees 13 regs during the j-loop). Non-atomic partials.
//
// Fast path (all labels zero, __ballot-detected): division-free predicates
//   iou>=0.5 <=> fma(inter,3,-ga) >= area_a+eps
//   iou<0.4  <=> fma(inter,3.5,-ga) < area_a+eps
// -> 13 VALU ops/pair, independent fmax chains. Slow path: exact argmax.
//
// ws layout: float2 partials[16][64] (b-major).

#define A_N 200000
#define B_N 16
#define G_N 32
#define APT 13
#define BLK 256
#define TILE (BLK * APT)                 // 3328
#define NBX 64                           // 64*3328 = 212992 >= 200000

#define C_POS (0.25f * 0.69314718f)      // alpha * ln2   (log2 -> ln fold)
#define C_NEG (0.75f * 0.69314718f)      // (1-alpha) * ln2

__launch_bounds__(BLK, 4)
__global__ void rnl_main(const float4* __restrict__ anchors,
                         const float* __restrict__ probs,
                         const float* __restrict__ y_true,
                         float2* __restrict__ partials) {
    __shared__ float4 sbox[G_N];        // gt corners {x1,y1,x2,y2}
    __shared__ float  snga[G_N];        // -ga
    __shared__ float  sga[G_N];         // ga   (slow path)
    __shared__ float  slab[G_N];        // label (slow path)
    __shared__ float  sraw[G_N * 5];
    __shared__ int    sflag;

    const int b = blockIdx.y;
    const int t = threadIdx.x;

    if (t < G_N * 5) sraw[t] = y_true[b * (G_N * 5) + t];
    __syncthreads();
    if (t < 64) {                          // wave 0 builds gt table + flag
        float lb = 0.0f;
        if (t < G_N) {
            float cx = sraw[t * 5 + 0], cy = sraw[t * 5 + 1];
            float w  = sraw[t * 5 + 2], h  = sraw[t * 5 + 3];
            lb = sraw[t * 5 + 4];
            float x1 = cx - 0.5f * w, y1 = cy - 0.5f * h;
            float x2 = cx + 0.5f * w, y2 = cy + 0.5f * h;
            float ga = (x2 - x1) * (y2 - y1);
            sbox[t] = make_float4(x1, y1, x2, y2);
            snga[t] = -ga; sga[t] = ga; slab[t] = lb;
        }
        unsigned long long bal = __ballot(lb != 0.0f);
        if (t == 0) sflag = (bal == 0ULL) ? 1 : 0;
    }
    __syncthreads();

    const int base = blockIdx.x * TILE + t;
    const float lab0 = slab[0];

    float loss = 0.0f, cnt = 0.0f;

    // anchors resident in regs for the whole j-loop (4*APT = 52 VGPR)
    float ax[APT], ay[APT], az[APT], aw[APT];
    #pragma unroll
    for (int k = 0; k < APT; ++k) {
        int idx  = base + k * BLK;
        int idxc = idx < A_N ? idx : A_N - 1;
        float4 an = anchors[idxc];
        ax[k] = an.x; ay[k] = an.y; az[k] = an.z; aw[k] = an.w;
    }

    if (sflag) {
        // ---- fast path: all labels zero -> 13 ops/pair, fmax-chain trackers
        float m1[APT], m2[APT];
        #pragma unroll
        for (int k = 0; k < APT; ++k) { m1[k] = -1e30f; m2[k] = -1e30f; }

        #pragma unroll 8
        for (int j = 0; j < G_N; ++j) {
            float4 gb  = sbox[j];
            float  nga = snga[j];
            #pragma unroll
            for (int k = 0; k < APT; ++k) {
                float ltx = fmaxf(ax[k], gb.x);
                float lty = fmaxf(ay[k], gb.y);
                float rbx = fminf(az[k], gb.z);
                float rby = fminf(aw[k], gb.w);
                float iw  = fmaxf(rbx - ltx, 0.0f);
                float ih  = fmaxf(rby - lty, 0.0f);
                float inter = iw * ih;
                m1[k] = fmaxf(m1[k], fmaf(inter, 3.0f, nga));
                m2[k] = fmaxf(m2[k], fmaf(inter, 3.5f, nga));
            }
        }
        #pragma unroll
        for (int k = 0; k < APT; ++k) {
            int idx  = base + k * BLK;
            bool valid = idx < A_N;
            int idxc = valid ? idx : A_N - 1;
            float sa = (az[k] - ax[k]) * (aw[k] - ay[k]) + 1e-8f;
            bool pos = m1[k] >= sa;             // max iou >= 0.5
            bool neg = m2[k] <  sa;             // max iou <  0.4
            float p = __builtin_amdgcn_fmed3f(probs[b * A_N + idxc], 1e-7f, 1.0f - 1e-7f);
            float q = 1.0f - p;
            float x = pos ? p : q;              // label==0 -> pos implies target hit
            float w = pos ? C_POS * q * q : C_NEG * p * p;
            float l = w * (-__log2f(x));
            l = ((pos | neg) && valid) ? l : 0.0f;
            loss += l;
            cnt  += (pos && valid) ? 1.0f : 0.0f;
        }
    } else {
        // ---- slow path: exact argmax + label (general correctness)
        float bi[APT], bS[APT], bl[APT];
        #pragma unroll
        for (int k = 0; k < APT; ++k) { bi[k] = 0.0f; bS[k] = 1.0f; bl[k] = lab0; }

        #pragma unroll 4
        for (int j = 0; j < G_N; ++j) {
            float4 gb = sbox[j];
            float  ga = sga[j];
            float  lb = slab[j];
            #pragma unroll
            for (int k = 0; k < APT; ++k) {
                float ltx = fmaxf(ax[k], gb.x);
                float lty = fmaxf(ay[k], gb.y);
                float rbx = fminf(az[k], gb.z);
                float rby = fminf(aw[k], gb.w);
                float iw  = fmaxf(rbx - ltx, 0.0f);
                float ih  = fmaxf(rby - lty, 0.0f);
                float inter = iw * ih;
                float sa = (az[k] - ax[k]) * (aw[k] - ay[k]) + 1e-8f;
                float S  = sa + ga;
                // iou_j > iou_best <=> inter_j*S_best > inter_best*S_j
                bool better = inter * bS[k] > bi[k] * S;
                bi[k] = better ? inter : bi[k];
                bS[k] = better ? S     : bS[k];
                bl[k] = better ? lb    : bl[k];
            }
        }
        #pragma unroll
        for (int k = 0; k < APT; ++k) {
            int idx  = base + k * BLK;
            bool valid = idx < A_N;
            int idxc = valid ? idx : A_N - 1;
            bool pos = 3.0f * bi[k] >= bS[k];   // max iou >= 0.5
            bool neg = 3.5f * bi[k] <  bS[k];   // max iou <  0.4
            bool tp  = pos && (bl[k] == 0.0f);  // one_hot(assigned, C=1) hit
            float p = __builtin_amdgcn_fmed3f(probs[b * A_N + idxc], 1e-7f, 1.0f - 1e-7f);
            float q = 1.0f - p;
            float x = tp ? p : q;
            float w = tp ? C_POS * q * q : C_NEG * p * p;
            float l = w * (-__log2f(x));
            l = ((pos | neg) && valid) ? l : 0.0f;
            loss += l;
            cnt  += (pos && valid) ? 1.0f : 0.0f;
        }
    }

    // block reduction: wave shuffle, then cross-wave via LDS, ONE float2 store
    #pragma unroll
    for (int off = 32; off > 0; off >>= 1) {
        loss += __shfl_down(loss, off);
        cnt  += __shfl_down(cnt, off);
    }
    __shared__ float s_l[4], s_c[4];
    int wid  = t >> 6;
    int lane = t & 63;
    if (lane == 0) { s_l[wid] = loss; s_c[wid] = cnt; }
    __syncthreads();
    if (t == 0) {
        float L = s_l[0] + s_l[1] + s_l[2] + s_l[3];
        float C = s_c[0] + s_c[1] + s_c[2] + s_c[3];
        partials[b * NBX + blockIdx.x] = make_float2(L, C);   // no atomics
    }
}

// ---------------- reduce: per-image sums + mean ----------------
__global__ void rnl_reduce(const float2* __restrict__ partials,
                           float* __restrict__ out) {
    const int t = threadIdx.x;          // 256 = 16 images x 16 lanes
    const int img = t >> 4, lane16 = t & 15;
    float L = 0.0f, C = 0.0f;
    for (int i = lane16; i < NBX; i += 16) {
        float2 p = partials[img * NBX + i];
        L += p.x; C += p.y;
    }
    #pragma unroll
    for (int m = 8; m > 0; m >>= 1) {
        L += __shfl_xor(L, m, 16);
        C += __shfl_xor(C, m, 16);
    }
    __shared__ float sl[B_N], sc[B_N];
    if (lane16 == 0) { sl[img] = L; sc[img] = C; }
    __syncthreads();
    if (t == 0) {
        float s = 0.0f;
        #pragma unroll
        for (int b = 0; b < B_N; ++b) s += sl[b] / fmaxf(sc[b], 1.0f);
        out[0] = s * (1.0f / (float)B_N);
    }
}

extern "C" void kernel_launch(void* const* d_in, const int* in_sizes, int n_in,
                              void* d_out, int out_size, void* d_ws, size_t ws_size,
                              hipStream_t stream) {
    const float* y_true     = (const float*)d_in[0];
    const float* y_classifs = (const float*)d_in[1];
    // d_in[2] = y_regressions: unused by the loss
    const float* anchors    = (const float*)d_in[3];
    float2* partials = (float2*)d_ws;

    dim3 grid(NBX, B_N);
    rnl_main<<<grid, BLK, 0, stream>>>((const float4*)anchors, y_classifs,
                                       y_true, partials);

    rnl_reduce<<<1, 256, 0, stream>>>(partials, (float*)d_out);
}

// Round 13
// 73.440 us; speedup vs baseline: 1.0688x; 1.0688x over previous
//
#include <hip/hip_runtime.h>
#include <hip/hip_bf16.h>

// RetinaNet focal classification loss, MI355X. Output: scalar f32.
//
// Round-13: consolidation. rnl_main is BYTE-IDENTICAL to round-7 (the proven
// 64-VGPR, 40.7us codegen; r11/r12 showed any perturbation risks a 240-VGPR
// hoist or a 64-VGPR+spill lottery). Only the tail changes: rnl_final's
// serial 1-thread 32-load loop becomes a 64-thread shuffle reduce.
//
// Fast path (all labels zero, __ballot-detected): division-free predicates
//   iou>=0.5 <=> fma(inter,3,-ga) >= area_a+eps
//   iou<0.4  <=> fma(inter,3.5,-ga) < area_a+eps
// -> 13 VALU ops/pair, independent fmax chains. Slow path: exact argmax.
//
// ws: 32 floats: [0..15] per-image loss sums, [16..31] per-image pos counts.

#define A_N 200000
#define B_N 16
#define G_N 32
#define APT 8
#define BLK 256
#define TILE (BLK * APT)                 // 2048
#define NBX ((A_N + TILE - 1) / TILE)    // 98

#define C_POS (0.25f * 0.69314718f)      // alpha * ln2   (log2 -> ln fold)
#define C_NEG (0.75f * 0.69314718f)      // (1-alpha) * ln2

__launch_bounds__(BLK)
__global__ void rnl_main(const float4* __restrict__ anchors,
                         const float* __restrict__ probs,
                         const float* __restrict__ y_true,
                         float* __restrict__ ws) {
    __shared__ float4 sbox[G_N];        // gt corners {x1,y1,x2,y2}
    __shared__ float  snga[G_N];        // -ga
    __shared__ float  sga[G_N];         // ga   (slow path)
    __shared__ float  slab[G_N];        // label (slow path)
    __shared__ float  sraw[G_N * 5];
    __shared__ int    sflag;

    const int b = blockIdx.y;
    const int t = threadIdx.x;

    if (t < G_N * 5) sraw[t] = y_true[b * (G_N * 5) + t];
    __syncthreads();
    if (t < 64) {                          // wave 0 builds gt table + flag
        float lb = 0.0f;
        if (t < G_N) {
            float cx = sraw[t * 5 + 0], cy = sraw[t * 5 + 1];
            float w  = sraw[t * 5 + 2], h  = sraw[t * 5 + 3];
            lb = sraw[t * 5 + 4];
            float x1 = cx - 0.5f * w, y1 = cy - 0.5f * h;
            float x2 = cx + 0.5f * w, y2 = cy + 0.5f * h;
            float ga = (x2 - x1) * (y2 - y1);
            sbox[t] = make_float4(x1, y1, x2, y2);
            snga[t] = -ga; sga[t] = ga; slab[t] = lb;
        }
        unsigned long long bal = __ballot(lb != 0.0f);
        if (t == 0) sflag = (bal == 0ULL) ? 1 : 0;
    }
    __syncthreads();

    const int base = blockIdx.x * TILE + t;
    const float lab0 = slab[0];

    float loss = 0.0f, cnt = 0.0f;

    // anchors + probs resident in regs for the whole j-loop
    float ax[APT], ay[APT], az[APT], aw[APT], pv[APT];
    #pragma unroll
    for (int k = 0; k < APT; ++k) {
        int idx  = base + k * BLK;
        int idxc = idx < A_N ? idx : A_N - 1;
        float4 an = anchors[idxc];
        ax[k] = an.x; ay[k] = an.y; az[k] = an.z; aw[k] = an.w;
        pv[k] = probs[b * A_N + idxc];
    }

    if (sflag) {
        // ---- fast path: all labels zero -> 13 ops/pair, fmax-chain trackers
        float m1[APT], m2[APT];
        #pragma unroll
        for (int k = 0; k < APT; ++k) { m1[k] = -1e30f; m2[k] = -1e30f; }

        #pragma unroll
        for (int j = 0; j < G_N; ++j) {
            float4 gb  = sbox[j];
            float  nga = snga[j];
            #pragma unroll
            for (int k = 0; k < APT; ++k) {
                float ltx = fmaxf(ax[k], gb.x);
                float lty = fmaxf(ay[k], gb.y);
                float rbx = fminf(az[k], gb.z);
                float rby = fminf(aw[k], gb.w);
                float iw  = fmaxf(rbx - ltx, 0.0f);
                float ih  = fmaxf(rby - lty, 0.0f);
                float inter = iw * ih;
                m1[k] = fmaxf(m1[k], fmaf(inter, 3.0f, nga));
                m2[k] = fmaxf(m2[k], fmaf(inter, 3.5f, nga));
            }
        }
        #pragma unroll
        for (int k = 0; k < APT; ++k) {
            bool valid = (base + k * BLK) < A_N;
            float sa = (az[k] - ax[k]) * (aw[k] - ay[k]) + 1e-8f;
            bool pos = m1[k] >= sa;             // max iou >= 0.5
            bool neg = m2[k] <  sa;             // max iou <  0.4
            float p = __builtin_amdgcn_fmed3f(pv[k], 1e-7f, 1.0f - 1e-7f);
            float q = 1.0f - p;
            float x = pos ? p : q;              // label==0 -> pos implies target hit
            float w = pos ? C_POS * q * q : C_NEG * p * p;
            float l = w * (-__log2f(x));
            l = ((pos | neg) && valid) ? l : 0.0f;
            loss += l;
            cnt  += (pos && valid) ? 1.0f : 0.0f;
        }
    } else {
        // ---- slow path: exact argmax + label (general correctness)
        float bi[APT], bS[APT], bl[APT];
        #pragma unroll
        for (int k = 0; k < APT; ++k) { bi[k] = 0.0f; bS[k] = 1.0f; bl[k] = lab0; }

        #pragma unroll
        for (int j = 0; j < G_N; ++j) {
            float4 gb = sbox[j];
            float  ga = sga[j];
            float  lb = slab[j];
            #pragma unroll
            for (int k = 0; k < APT; ++k) {
                float ltx = fmaxf(ax[k], gb.x);
                float lty = fmaxf(ay[k], gb.y);
                float rbx = fminf(az[k], gb.z);
                float rby = fminf(aw[k], gb.w);
                float iw  = fmaxf(rbx - ltx, 0.0f);
                float ih  = fmaxf(rby - lty, 0.0f);
                float inter = iw * ih;
                float sa = (az[k] - ax[k]) * (aw[k] - ay[k]) + 1e-8f;
                float S  = sa + ga;
                // iou_j > iou_best <=> inter_j*S_best > inter_best*S_j
                bool better = inter * bS[k] > bi[k] * S;
                bi[k] = better ? inter : bi[k];
                bS[k] = better ? S     : bS[k];
                bl[k] = better ? lb    : bl[k];
            }
        }
        #pragma unroll
        for (int k = 0; k < APT; ++k) {
            bool valid = (base + k * BLK) < A_N;
            bool pos = 3.0f * bi[k] >= bS[k];   // max iou >= 0.5
            bool neg = 3.5f * bi[k] <  bS[k];   // max iou <  0.4
            bool tp  = pos && (bl[k] == 0.0f);  // one_hot(assigned, C=1) hit
            float p = __builtin_amdgcn_fmed3f(pv[k], 1e-7f, 1.0f - 1e-7f);
            float q = 1.0f - p;
            float x = tp ? p : q;
            float w = tp ? C_POS * q * q : C_NEG * p * p;
            float l = w * (-__log2f(x));
            l = ((pos | neg) && valid) ? l : 0.0f;
            loss += l;
            cnt  += (pos && valid) ? 1.0f : 0.0f;
        }
    }

    // block reduction: wave shuffle, then cross-wave via LDS, 2 atomics/block
    #pragma unroll
    for (int off = 32; off > 0; off >>= 1) {
        loss += __shfl_down(loss, off);
        cnt  += __shfl_down(cnt, off);
    }
    __shared__ float s_l[4], s_c[4];
    int wid  = t >> 6;
    int lane = t & 63;
    if (lane == 0) { s_l[wid] = loss; s_c[wid] = cnt; }
    __syncthreads();
    if (t == 0) {
        atomicAdd(&ws[b],       s_l[0] + s_l[1] + s_l[2] + s_l[3]);
        atomicAdd(&ws[B_N + b], s_c[0] + s_c[1] + s_c[2] + s_c[3]);
    }
}

// ---------------- final: parallel mean over images (64-thread reduce) ----------------
__global__ void rnl_final(const float* __restrict__ ws, float* __restrict__ out) {
    const int t = threadIdx.x;            // 64 threads; lanes 0..15 active
    float v = 0.0f;
    if (t < B_N) v = ws[t] / fmaxf(ws[B_N + t], 1.0f);
    #pragma unroll
    for (int m = 8; m > 0; m >>= 1) v += __shfl_xor(v, m, 16);
    if (t == 0) out[0] = v * (1.0f / (float)B_N);
}

extern "C" void kernel_launch(void* const* d_in, const int* in_sizes, int n_in,
                              void* d_out, int out_size, void* d_ws, size_t ws_size,
                              hipStream_t stream) {
    const float* y_true     = (const float*)d_in[0];
    const float* y_classifs = (const float*)d_in[1];
    // d_in[2] = y_regressions: unused by the loss
    const float* anchors    = (const float*)d_in[3];
    float* ws = (float*)d_ws;

    hipMemsetAsync(ws, 0, 2 * B_N * sizeof(float), stream);  // capturable memset node

    dim3 grid(NBX, B_N);
    rnl_main<<<grid, BLK, 0, stream>>>((const float4*)anchors, y_classifs,
                                       y_true, ws);

    rnl_final<<<1, 64, 0, stream>>>(ws, (float*)d_out);
}

// Round 14
// 63.614 us; speedup vs baseline: 1.2339x; 1.1545x over previous
//
#include <hip/hip_runtime.h>
#include <hip/hip_bf16.h>

// RetinaNet focal classification loss, MI355X. Output: scalar f32.
//
// Round-14: defeat the codegen lottery BY CONSTRUCTION.
// Evidence r7..r13: identical j-loop source compiles to 64 / 68 / 240 / 240
// VGPR depending on unrelated TU edits (co-compiled-kernel perturbation).
// The 240-hoist = compiler pre-loading all 32 fully-unrolled iterations' LDS
// gt values into regs. Fix: #pragma unroll 1 on the j-loop with an explicit
// 1-deep software prefetch (gb/nga rotate) -> hoist window is 10 regs, hard
// bound, schedule-independent. Plus r12's residency shaping done right:
// APT=13, grid 64x16 = 1024 blocks = exactly 4 blocks/CU (VGPR ~105 -> 128
// bucket -> 4 waves/SIMD), single dispatch round, no partial-round tail.
//
// Fast path (all labels zero, __ballot-detected): division-free predicates
//   iou>=0.5 <=> fma(inter,3,-ga) >= area_a+eps
//   iou<0.4  <=> fma(inter,3.5,-ga) < area_a+eps
// -> 13 VALU ops/pair, independent fmax chains. Slow path: exact argmax.
//
// ws: 32 floats: [0..15] per-image loss sums, [16..31] per-image pos counts.

#define A_N 200000
#define B_N 16
#define G_N 32
#define APT 13
#define BLK 256
#define TILE (BLK * APT)                 // 3328
#define NBX 64                           // 64*3328 = 212992 >= 200000; grid 64x16 = 1024 blocks

#define C_POS (0.25f * 0.69314718f)      // alpha * ln2   (log2 -> ln fold)
#define C_NEG (0.75f * 0.69314718f)      // (1-alpha) * ln2

__launch_bounds__(BLK)
__global__ void rnl_main(const float4* __restrict__ anchors,
                         const float* __restrict__ probs,
                         const float* __restrict__ y_true,
                         float* __restrict__ ws) {
    __shared__ float4 sbox[G_N];        // gt corners {x1,y1,x2,y2}
    __shared__ float  snga[G_N];        // -ga
    __shared__ float  sga[G_N];         // ga   (slow path)
    __shared__ float  slab[G_N];        // label (slow path)
    __shared__ float  sraw[G_N * 5];
    __shared__ int    sflag;

    const int b = blockIdx.y;
    const int t = threadIdx.x;

    if (t < G_N * 5) sraw[t] = y_true[b * (G_N * 5) + t];
    __syncthreads();
    if (t < 64) {                          // wave 0 builds gt table + flag
        float lb = 0.0f;
        if (t < G_N) {
            float cx = sraw[t * 5 + 0], cy = sraw[t * 5 + 1];
            float w  = sraw[t * 5 + 2], h  = sraw[t * 5 + 3];
            lb = sraw[t * 5 + 4];
            float x1 = cx - 0.5f * w, y1 = cy - 0.5f * h;
            float x2 = cx + 0.5f * w, y2 = cy + 0.5f * h;
            float ga = (x2 - x1) * (y2 - y1);
            sbox[t] = make_float4(x1, y1, x2, y2);
            snga[t] = -ga; sga[t] = ga; slab[t] = lb;
        }
        unsigned long long bal = __ballot(lb != 0.0f);
        if (t == 0) sflag = (bal == 0ULL) ? 1 : 0;
    }
    __syncthreads();

    const int base = blockIdx.x * TILE + t;
    const float lab0 = slab[0];

    float loss = 0.0f, cnt = 0.0f;

    // anchors resident in regs for the whole j-loop (4*APT = 52 VGPR)
    float ax[APT], ay[APT], az[APT], aw[APT];
    #pragma unroll
    for (int k = 0; k < APT; ++k) {
        int idx  = base + k * BLK;
        int idxc = idx < A_N ? idx : A_N - 1;
        float4 an = anchors[idxc];
        ax[k] = an.x; ay[k] = an.y; az[k] = an.z; aw[k] = an.w;
    }

    if (sflag) {
        // ---- fast path: all labels zero -> 13 ops/pair, fmax-chain trackers
        float m1[APT], m2[APT];
        #pragma unroll
        for (int k = 0; k < APT; ++k) { m1[k] = -1e30f; m2[k] = -1e30f; }

        float4 gb  = sbox[0];
        float  nga = snga[0];
        #pragma unroll 1                   // HARD bound on LDS-value hoisting
        for (int j = 0; j < G_N; ++j) {
            int jn = (j + 1) & (G_N - 1);  // prefetch next (wraps harmlessly)
            float4 gbn  = sbox[jn];
            float  ngan = snga[jn];
            #pragma unroll
            for (int k = 0; k < APT; ++k) {
                float ltx = fmaxf(ax[k], gb.x);
                float lty = fmaxf(ay[k], gb.y);
                float rbx = fminf(az[k], gb.z);
                float rby = fminf(aw[k], gb.w);
                float iw  = fmaxf(rbx - ltx, 0.0f);
                float ih  = fmaxf(rby - lty, 0.0f);
                float inter = iw * ih;
                m1[k] = fmaxf(m1[k], fmaf(inter, 3.0f, nga));
                m2[k] = fmaxf(m2[k], fmaf(inter, 3.5f, nga));
            }
            gb = gbn; nga = ngan;
        }
        #pragma unroll
        for (int k = 0; k < APT; ++k) {
            int idx  = base + k * BLK;
            bool valid = idx < A_N;
            int idxc = valid ? idx : A_N - 1;
            float sa = (az[k] - ax[k]) * (aw[k] - ay[k]) + 1e-8f;
            bool pos = m1[k] >= sa;             // max iou >= 0.5
            bool neg = m2[k] <  sa;             // max iou <  0.4
            float p = __builtin_amdgcn_fmed3f(probs[b * A_N + idxc], 1e-7f, 1.0f - 1e-7f);
            float q = 1.0f - p;
            float x = pos ? p : q;              // label==0 -> pos implies target hit
            float w = pos ? C_POS * q * q : C_NEG * p * p;
            float l = w * (-__log2f(x));
            l = ((pos | neg) && valid) ? l : 0.0f;
            loss += l;
            cnt  += (pos && valid) ? 1.0f : 0.0f;
        }
    } else {
        // ---- slow path: exact argmax + label (general correctness)
        float bi[APT], bS[APT], bl[APT];
        #pragma unroll
        for (int k = 0; k < APT; ++k) { bi[k] = 0.0f; bS[k] = 1.0f; bl[k] = lab0; }

        float4 gb = sbox[0];
        float  ga = sga[0];
        float  lb = slab[0];
        #pragma unroll 1
        for (int j = 0; j < G_N; ++j) {
            int jn = (j + 1) & (G_N - 1);
            float4 gbn = sbox[jn];
            float  gan = sga[jn];
            float  lbn = slab[jn];
            #pragma unroll
            for (int k = 0; k < APT; ++k) {
                float ltx = fmaxf(ax[k], gb.x);
                float lty = fmaxf(ay[k], gb.y);
                float rbx = fminf(az[k], gb.z);
                float rby = fminf(aw[k], gb.w);
                float iw  = fmaxf(rbx - ltx, 0.0f);
                float ih  = fmaxf(rby - lty, 0.0f);
                float inter = iw * ih;
                float sa = (az[k] - ax[k]) * (aw[k] - ay[k]) + 1e-8f;
                float S  = sa + ga;
                // iou_j > iou_best <=> inter_j*S_best > inter_best*S_j
                bool better = inter * bS[k] > bi[k] * S;
                bi[k] = better ? inter : bi[k];
                bS[k] = better ? S     : bS[k];
                bl[k] = better ? lb    : bl[k];
            }
            gb = gbn; ga = gan; lb = lbn;
        }
        #pragma unroll
        for (int k = 0; k < APT; ++k) {
            int idx  = base + k * BLK;
            bool valid = idx < A_N;
            int idxc = valid ? idx : A_N - 1;
            bool pos = 3.0f * bi[k] >= bS[k];   // max iou >= 0.5
            bool neg = 3.5f * bi[k] <  bS[k];   // max iou <  0.4
            bool tp  = pos && (bl[k] == 0.0f);  // one_hot(assigned, C=1) hit
            float p = __builtin_amdgcn_fmed3f(probs[b * A_N + idxc], 1e-7f, 1.0f - 1e-7f);
            float q = 1.0f - p;
            float x = tp ? p : q;
            float w = tp ? C_POS * q * q : C_NEG * p * p;
            float l = w * (-__log2f(x));
            l = ((pos | neg) && valid) ? l : 0.0f;
            loss += l;
            cnt  += (pos && valid) ? 1.0f : 0.0f;
        }
    }

    // block reduction: wave shuffle, then cross-wave via LDS, 2 atomics/block
    #pragma unroll
    for (int off = 32; off > 0; off >>= 1) {
        loss += __shfl_down(loss, off);
        cnt  += __shfl_down(cnt, off);
    }
    __shared__ float s_l[4], s_c[4];
    int wid  = t >> 6;
    int lane = t & 63;
    if (lane == 0) { s_l[wid] = loss; s_c[wid] = cnt; }
    __syncthreads();
    if (t == 0) {
        atomicAdd(&ws[b],       s_l[0] + s_l[1] + s_l[2] + s_l[3]);
        atomicAdd(&ws[B_N + b], s_c[0] + s_c[1] + s_c[2] + s_c[3]);
    }
}

// ---------------- final: mean over images (one wave) ----------------
__global__ void rnl_final(const float* __restrict__ ws, float* __restrict__ out) {
    const int t = threadIdx.x;            // 64 threads; lanes 0..15 active
    float v = 0.0f;
    if (t < B_N) v = ws[t] / fmaxf(ws[B_N + t], 1.0f);
    #pragma unroll
    for (int m = 8; m > 0; m >>= 1) v += __shfl_xor(v, m, 16);
    if (t == 0) out[0] = v * (1.0f / (float)B_N);
}

extern "C" void kernel_launch(void* const* d_in, const int* in_sizes, int n_in,
                              void* d_out, int out_size, void* d_ws, size_t ws_size,
                              hipStream_t stream) {
    const float* y_true     = (const float*)d_in[0];
    const float* y_classifs = (const float*)d_in[1];
    // d_in[2] = y_regressions: unused by the loss
    const float* anchors    = (const float*)d_in[3];
    float* ws = (float*)d_ws;

    hipMemsetAsync(ws, 0, 2 * B_N * sizeof(float), stream);  // capturable memset node

    dim3 grid(NBX, B_N);
    rnl_main<<<grid, BLK, 0, stream>>>((const float4*)anchors, y_classifs,
                                       y_true, ws);

    rnl_final<<<1, 64, 0, stream>>>(ws, (float*)d_out);
}